// Round 1
// 821.566 us; speedup vs baseline: 1.0056x; 1.0056x over previous
//
#include <hip/hip_runtime.h>

#define BLOCK 256
#define GRID 2048
// 8192 rows split into 4 bins of 2048 rows: bin = x >> 11.
// Per-pass live footprint: 2048*8192*4B*2 arrays = 128 MB (fits 256 MB L3
// together with the 80 MB streamed index re-read). Repeated lines within a
// pass hit L3 instead of HBM (avg 2.39 draws/line -> ~38% fewer line fetches).
#define LOG_RPB 11
#define NB 4

__global__ __launch_bounds__(BLOCK) void dti_pu_loss_kernel(
    const float* __restrict__ R,      // drug_protein_reconstruct
    const float* __restrict__ D,      // drug_protein
    const float* __restrict__ alpha,  // 1 element
    const int* __restrict__ px, const int* __restrict__ py, int npos,
    const int* __restrict__ nx, const int* __restrict__ ny, int nneg,
    float* __restrict__ out)
{
    const int tid    = blockIdx.x * BLOCK + threadIdx.x;
    const int stride = GRID * BLOCK;

    float pos_acc = 0.0f;
    float neg_acc = 0.0f;

    const int np4 = npos >> 2;
    const int nn4 = nneg >> 2;
    const int4* __restrict__ px4 = (const int4*)px;
    const int4* __restrict__ py4 = (const int4*)py;
    const int4* __restrict__ nx4 = (const int4*)nx;
    const int4* __restrict__ ny4 = (const int4*)ny;

    // ---- 4 passes over the index streams; each pass gathers only rows in
    // ---- its bin so the live matrix slice stays L3-resident.
    #pragma unroll 1
    for (int p = 0; p < NB; ++p) {
        #pragma unroll 1
        for (int i = tid; i < np4; i += stride) {
            int4 xs = px4[i];
            int4 ys = py4[i];
            if ((xs.x >> LOG_RPB) == p) { int o = (xs.x << 13) + ys.x; float d = R[o] - D[o]; pos_acc += d * d; }
            if ((xs.y >> LOG_RPB) == p) { int o = (xs.y << 13) + ys.y; float d = R[o] - D[o]; pos_acc += d * d; }
            if ((xs.z >> LOG_RPB) == p) { int o = (xs.z << 13) + ys.z; float d = R[o] - D[o]; pos_acc += d * d; }
            if ((xs.w >> LOG_RPB) == p) { int o = (xs.w << 13) + ys.w; float d = R[o] - D[o]; pos_acc += d * d; }
        }
        #pragma unroll 1
        for (int i = tid; i < nn4; i += stride) {
            int4 xs = nx4[i];
            int4 ys = ny4[i];
            if ((xs.x >> LOG_RPB) == p) { int o = (xs.x << 13) + ys.x; float d = R[o] - D[o]; neg_acc += d * d; }
            if ((xs.y >> LOG_RPB) == p) { int o = (xs.y << 13) + ys.y; float d = R[o] - D[o]; neg_acc += d * d; }
            if ((xs.z >> LOG_RPB) == p) { int o = (xs.z << 13) + ys.z; float d = R[o] - D[o]; neg_acc += d * d; }
            if ((xs.w >> LOG_RPB) == p) { int o = (xs.w << 13) + ys.w; float d = R[o] - D[o]; neg_acc += d * d; }
        }
    }

    // ---- scalar tails (all bins at once; counts here are 0 for the given
    // ---- sizes since npos/nneg are multiples of 4, kept for safety)
    for (int i = (np4 << 2) + tid; i < npos; i += stride) {
        int o = (px[i] << 13) + py[i];
        float d = R[o] - D[o];
        pos_acc += d * d;
    }
    for (int i = (nn4 << 2) + tid; i < nneg; i += stride) {
        int o = (nx[i] << 13) + ny[i];
        float d = R[o] - D[o];
        neg_acc += d * d;
    }

    // ---- combine with alpha (linear => per-thread combine is exact) ----
    const float a = alpha[0];
    float v = pos_acc * ((1.0f - a) * 0.5f) + neg_acc * (a * 0.5f);

    // ---- wave reduce (64 lanes) ----
    #pragma unroll
    for (int off = 32; off > 0; off >>= 1)
        v += __shfl_down(v, off, 64);

    // ---- block reduce via LDS, one atomic per block ----
    __shared__ float sdata[BLOCK / 64];
    const int lane = threadIdx.x & 63;
    const int wave = threadIdx.x >> 6;
    if (lane == 0) sdata[wave] = v;
    __syncthreads();
    if (threadIdx.x == 0) {
        float s = 0.0f;
        #pragma unroll
        for (int w = 0; w < BLOCK / 64; ++w) s += sdata[w];
        atomicAdd(out, s);
    }
}

extern "C" void kernel_launch(void* const* d_in, const int* in_sizes, int n_in,
                              void* d_out, int out_size, void* d_ws, size_t ws_size,
                              hipStream_t stream) {
    const float* R     = (const float*)d_in[0];
    const float* D     = (const float*)d_in[1];
    const float* alpha = (const float*)d_in[2];
    const int*   px    = (const int*)d_in[3];
    const int*   py    = (const int*)d_in[4];
    const int*   nx    = (const int*)d_in[5];
    const int*   ny    = (const int*)d_in[6];
    const int    npos  = in_sizes[3];
    const int    nneg  = in_sizes[5];

    float* out = (float*)d_out;

    // d_out is poisoned with 0xAA before every timed launch — zero it.
    hipMemsetAsync(out, 0, sizeof(float), stream);

    dti_pu_loss_kernel<<<GRID, BLOCK, 0, stream>>>(
        R, D, alpha, px, py, npos, nx, ny, nneg, out);
}